// Round 10
// baseline (240.377 us; speedup 1.0000x reference)
//
#include <hip/hip_runtime.h>

#define N_ROWS 4096
#define D_DIM  512
#define ROWB   512              // bytes per fp8 row
#define C_ROWS 8192
#define BM 256
#define BN 128
#define BKB 64                  // K-tile bytes = 64 fp8 elems
#define NKT 8                   // 512 / 64
#define GXf (C_ROWS / BN)       // 64
#define GYf (N_ROWS / BM)       // 16
#define NBLK (GXf * GYf)        // 1024

typedef __attribute__((ext_vector_type(4))) float f32x4;
typedef __attribute__((ext_vector_type(2))) long  i64x2;    // one ds_read_b128

#define AS1 __attribute__((address_space(1)))
#define AS3 __attribute__((address_space(3)))

__device__ __forceinline__ void gload_lds16(const void* g, void* l) {
    __builtin_amdgcn_global_load_lds((const AS1 unsigned int*)g,
                                     (AS3 unsigned int*)l, 16, 0, 0);
}

// ---------------- l2-normalize rows, fp32 -> fp8 e4m3, k-permuted ----------
// k-permutation (within each 64-elem block): dest byte q*16+h*8+b holds
// orig k = q*8 + h*32 + b.  Same permutation for f and c => dots invariant.
__global__ __launch_bounds__(256) void normalize_kernel(
        const float* __restrict__ feat, const float* __restrict__ cent,
        unsigned char* __restrict__ fN, unsigned char* __restrict__ cN) {
    const int w    = threadIdx.x >> 6;
    const int lane = threadIdx.x & 63;
    const int row  = blockIdx.x * 4 + w;      // 0 .. 12287

    const float* src = (row < N_ROWS) ? feat + (size_t)row * D_DIM
                                      : cent + (size_t)(row - N_ROWS) * D_DIM;
    unsigned char* dst = (row < N_ROWS) ? fN + (size_t)row * ROWB
                                        : cN + (size_t)(row - N_ROWS) * ROWB;

    const float* r = src + lane * 8;
    float4 v0 = *(const float4*)(r);
    float4 v1 = *(const float4*)(r + 4);
    float ss = v0.x*v0.x + v0.y*v0.y + v0.z*v0.z + v0.w*v0.w
             + v1.x*v1.x + v1.y*v1.y + v1.z*v1.z + v1.w*v1.w;
    #pragma unroll
    for (int off = 32; off; off >>= 1) ss += __shfl_xor(ss, off);
    const float sc = 1.0f / fmaxf(sqrtf(ss), 1e-12f);

    int p0 = __builtin_amdgcn_cvt_pk_fp8_f32(v0.x * sc, v0.y * sc, 0, false);
    p0     = __builtin_amdgcn_cvt_pk_fp8_f32(v0.z * sc, v0.w * sc, p0, true);
    int p1 = __builtin_amdgcn_cvt_pk_fp8_f32(v1.x * sc, v1.y * sc, 0, false);
    p1     = __builtin_amdgcn_cvt_pk_fp8_f32(v1.z * sc, v1.w * sc, p1, true);

    // lane handles orig k = lane*8..+8 -> kb=lane>>3, q=lane&3, h=(lane>>2)&1
    const int db = ((lane >> 3) << 6) + ((lane & 3) << 4) + (((lane >> 2) & 1) << 3);
    uint2 o; o.x = (unsigned)p0; o.y = (unsigned)p1;
    *(uint2*)(dst + db) = o;
}

// ---------------- pos_dot[i] = fN[i] . cN[labels[i]]  (fp8 inputs) ---------
__global__ __launch_bounds__(256) void posdot_kernel(
        const unsigned char* __restrict__ fN, const unsigned char* __restrict__ cN,
        const int* __restrict__ labels, float* __restrict__ pos) {
    const int w    = threadIdx.x >> 6;
    const int lane = threadIdx.x & 63;
    const int i    = blockIdx.x * 4 + w;
    const int lab  = labels[i];

    const uint2 a = *(const uint2*)(fN + (size_t)i   * ROWB + lane * 8);
    const uint2 b = *(const uint2*)(cN + (size_t)lab * ROWB + lane * 8);
    float s = 0.0f;
    // byte-select operand must be a LITERAL constant -> fully expanded
    s += __builtin_amdgcn_cvt_f32_fp8((int)a.x, 0) * __builtin_amdgcn_cvt_f32_fp8((int)b.x, 0);
    s += __builtin_amdgcn_cvt_f32_fp8((int)a.x, 1) * __builtin_amdgcn_cvt_f32_fp8((int)b.x, 1);
    s += __builtin_amdgcn_cvt_f32_fp8((int)a.x, 2) * __builtin_amdgcn_cvt_f32_fp8((int)b.x, 2);
    s += __builtin_amdgcn_cvt_f32_fp8((int)a.x, 3) * __builtin_amdgcn_cvt_f32_fp8((int)b.x, 3);
    s += __builtin_amdgcn_cvt_f32_fp8((int)a.y, 0) * __builtin_amdgcn_cvt_f32_fp8((int)b.y, 0);
    s += __builtin_amdgcn_cvt_f32_fp8((int)a.y, 1) * __builtin_amdgcn_cvt_f32_fp8((int)b.y, 1);
    s += __builtin_amdgcn_cvt_f32_fp8((int)a.y, 2) * __builtin_amdgcn_cvt_f32_fp8((int)b.y, 2);
    s += __builtin_amdgcn_cvt_f32_fp8((int)a.y, 3) * __builtin_amdgcn_cvt_f32_fp8((int)b.y, 3);
    #pragma unroll
    for (int off = 32; off; off >>= 1) s += __shfl_xor(s, off);
    if (lane == 0) pos[i] = s;
}

// ---------------- fused fp8 GEMM + masked softplus reduction ----------------
// 256x128 tile, BK=64B, 8 waves (4M x 2N, wave tile 64x64), double-buffered,
// 2 barriers/K-tile, counted vmcnt(3), stage after mid-barrier.
// NEW (R10): XCD-stripe block mapping -- XCD k (= id&7, round-robin dispatch)
// owns col-tiles [k*8, k*8+8): per-XCD L2 footprint = 0.5 MB cN stripe +
// 2 MB fN = 2.5 MB < 4 MB -> staging served from L2 (~35 TB/s agg) instead
// of L3 (~6.3 TB/s).  Also 3 blocks/CU (launch_bounds(512,6); 48 KB LDS x3).
__global__ __launch_bounds__(512, 6) void fused_loss_kernel(
        const unsigned char* __restrict__ fN, const unsigned char* __restrict__ cN,
        const int* __restrict__ labels, const float* __restrict__ pos,
        float* __restrict__ partialL, unsigned int* __restrict__ partialC) {
    __shared__ __align__(16) unsigned char As[2][BM * BKB];   // 32 KB
    __shared__ __align__(16) unsigned char Bs[2][BN * BKB];   // 16 KB

    const int tid  = threadIdx.x;
    const int w    = tid >> 6;        // wave 0..7
    const int lane = tid & 63;
    const int wm   = w >> 1;          // 0..3  (M quarter: rows wm*64..+63)
    const int wn   = w & 1;           // 0..1  (N half:   cols wn*64..+63)

    // XCD-stripe mapping (bijective: 1024 = 8 xcd * 16 by * 8 c8)
    const int id  = blockIdx.x;       // 0..1023
    const int xcd = id & 7;
    const int loc = id >> 3;          // 0..127
    const int by  = loc & 15;         // inner: A rows sweep while B fixed
    const int c8  = loc >> 4;         // 0..7
    const int rowBase = by * BM;
    const int colBase = (xcd * 8 + c8) * BN;

    const int lr = lane & 15;
    const int kq = lane >> 4;         // 0..3 = 16B seg (both kk halves)

    // staging: chunk = 16 rows x 64B; lane l -> row l>>2, LDS seg l&3,
    // fetching pre-swizzled global seg (l&3)^f(l>>2), f(x)=(x^(x>>2))&3
    const int gseg = ((lane & 3) ^ ((lane >> 2) & 3) ^ ((lane >> 4) & 3));
    const unsigned char* aG = fN + (size_t)(rowBase + w * 32 + (lane >> 2)) * ROWB + gseg * 16;
    const unsigned char* bG = cN + (size_t)(colBase + w * 16 + (lane >> 2)) * ROWB + gseg * 16;

#define STAGE(buf, t)                                                        \
    do {                                                                     \
        gload_lds16(aG + (t) * BKB,             &As[buf][(w * 32) * BKB]);   \
        gload_lds16(aG + (t) * BKB + 16 * ROWB, &As[buf][(w * 32 + 16) * BKB]); \
        gload_lds16(bG + (t) * BKB,             &Bs[buf][(w * 16) * BKB]);   \
    } while (0)

    // read: lane wants global seg kq at row (16-aligned base + lr):
    // LDS seg = kq ^ f(lr);   b128 -> [kk=0 | kk=1] halves
    const int segrd = (lane ^ (lane >> 2) ^ (lane >> 4)) & 3;
    const int loff  = lr * BKB + segrd * 16;     // per-lane offset in tile

    f32x4 acc[4][4] = {};

    // prologue: tiles 0,1 in flight (6 loads/wave)
    STAGE(0, 0);
    STAGE(1, 1);
    asm volatile("s_waitcnt vmcnt(3)" ::: "memory");
    __builtin_amdgcn_s_barrier();

    #pragma unroll
    for (int t = 0; t < NKT; ++t) {
        const int cur = t & 1;

        i64x2 af[4], bb[4];
        #pragma unroll
        for (int m = 0; m < 4; ++m)
            af[m] = *(const i64x2*)&As[cur][(wm * 64 + m * 16) * BKB + loff];
        #pragma unroll
        for (int n = 0; n < 4; ++n)
            bb[n] = *(const i64x2*)&Bs[cur][(wn * 64 + n * 16) * BKB + loff];
        asm volatile("s_waitcnt lgkmcnt(0)" ::: "memory");
        __builtin_amdgcn_sched_barrier(0);
        __builtin_amdgcn_s_barrier();            // all waves done with buf[cur]

        if (t + 2 < NKT) STAGE(cur, t + 2);      // overwrite freed buffer

        #pragma unroll
        for (int kk = 0; kk < 2; ++kk)
            #pragma unroll
            for (int m = 0; m < 4; ++m)
                #pragma unroll
                for (int n = 0; n < 4; ++n)
                    acc[m][n] = __builtin_amdgcn_mfma_f32_16x16x32_fp8_fp8(
                                    af[m][kk], bb[n][kk], acc[m][n], 0, 0, 0);

        if (t < NKT - 1) {
            if (t < NKT - 2) asm volatile("s_waitcnt vmcnt(3)" ::: "memory");
            else             asm volatile("s_waitcnt vmcnt(0)" ::: "memory");
            __builtin_amdgcn_s_barrier();        // next tile landed chip-wide
        }
    }
#undef STAGE

    // ---- epilogue: x = S_ij - pos[i]; mask j != label[i]; softplus; sum ----
    float lsum = 0.0f;
    unsigned cnt = 0;
    #pragma unroll
    for (int m = 0; m < 4; ++m) {
        #pragma unroll
        for (int j = 0; j < 4; ++j) {
            const int gi = rowBase + wm * 64 + m * 16 + kq * 4 + j;
            const float p = pos[gi];
            const int lab = labels[gi];
            #pragma unroll
            for (int n = 0; n < 4; ++n) {
                const int gj = colBase + wn * 64 + n * 16 + lr;
                const float x = acc[m][n][j] - p;
                if (gj != lab) {
                    const float l = __logf(1.0f + __expf(x));   // softplus
                    if (l > 0.0f) { lsum += l; cnt++; }
                }
            }
        }
    }
    #pragma unroll
    for (int off = 32; off; off >>= 1) {
        lsum += __shfl_xor(lsum, off);
        cnt  += __shfl_xor(cnt,  off);
    }

    __syncthreads();                        // safe to reuse LDS
    float*    s_sum = (float*)&As[0][0];
    unsigned* s_cnt = (unsigned*)&As[0][64];
    if (lane == 0) { s_sum[w] = lsum; s_cnt[w] = cnt; }
    __syncthreads();
    if (tid == 0) {
        float    L = 0.0f;
        unsigned C = 0;
        #pragma unroll
        for (int i = 0; i < 8; ++i) { L += s_sum[i]; C += s_cnt[i]; }
        partialL[id] = L;
        partialC[id] = C;
    }
}

// ---------------- finalize: reduce 1024 per-block partials ----------------
__global__ __launch_bounds__(256) void finalize_kernel(
        const float* __restrict__ partialL, const unsigned int* __restrict__ partialC,
        float* __restrict__ out) {
    __shared__ float    s_sum[4];
    __shared__ unsigned s_cnt[4];
    const int w    = threadIdx.x >> 6;
    const int lane = threadIdx.x & 63;

    float s = 0.0f; unsigned c = 0;
    for (int i = threadIdx.x; i < NBLK; i += 256) { s += partialL[i]; c += partialC[i]; }
    #pragma unroll
    for (int off = 32; off; off >>= 1) {
        s += __shfl_xor(s, off);
        c += __shfl_xor(c, off);
    }
    if (lane == 0) { s_sum[w] = s; s_cnt[w] = c; }
    __syncthreads();
    if (threadIdx.x == 0) {
        const float    l = s_sum[0] + s_sum[1] + s_sum[2] + s_sum[3];
        const unsigned n = s_cnt[0] + s_cnt[1] + s_cnt[2] + s_cnt[3];
        out[0] = (n > 0u) ? l / (float)n : l;
    }
}

extern "C" void kernel_launch(void* const* d_in, const int* in_sizes, int n_in,
                              void* d_out, int out_size, void* d_ws, size_t ws_size,
                              hipStream_t stream) {
    const float* features = (const float*)d_in[0];   // [4096, 512]
    const float* centers  = (const float*)d_in[1];   // [8192, 512]
    const int*   labels   = (const int*)d_in[2];     // [4096]
    float* out = (float*)d_out;

    char* ws = (char*)d_ws;
    unsigned char* fN  = (unsigned char*)ws;                          // 2 MB
    unsigned char* cN  = (unsigned char*)(ws + (2u << 20));           // 4 MB
    float*         pos = (float*)(ws + (6u << 20));                   // 16 KB
    float*         partialL = (float*)(ws + (6u << 20) + (1u << 16));           // 4 KB
    unsigned int*  partialC = (unsigned int*)(ws + (6u << 20) + (1u << 16) + (1u << 14));

    normalize_kernel<<<(N_ROWS + C_ROWS) / 4, 256, 0, stream>>>(features, centers, fN, cN);
    posdot_kernel<<<N_ROWS / 4, 256, 0, stream>>>(fN, cN, labels, pos);

    fused_loss_kernel<<<NBLK, 512, 0, stream>>>(fN, cN, labels, pos, partialL, partialC);

    finalize_kernel<<<1, 256, 0, stream>>>(partialL, partialC, out);
}

// Round 11
// 52.880 us; speedup vs baseline: 4.5457x; 4.5457x over previous
//
#include <hip/hip_runtime.h>

#define N_ROWS 4096
#define D_DIM  512
#define ROWB   512              // bytes per fp8 row
#define C_ROWS 8192
#define BM 256
#define BN 128
#define BKB 64                  // K-tile bytes = 64 fp8 elems
#define NKT 8                   // 512 / 64
#define GXf (C_ROWS / BN)       // 64
#define GYf (N_ROWS / BM)       // 16
#define NBLK (GXf * GYf)        // 1024

typedef __attribute__((ext_vector_type(4))) float f32x4;
typedef __attribute__((ext_vector_type(2))) long  i64x2;    // one ds_read_b128

#define AS1 __attribute__((address_space(1)))
#define AS3 __attribute__((address_space(3)))

__device__ __forceinline__ void gload_lds16(const void* g, void* l) {
    __builtin_amdgcn_global_load_lds((const AS1 unsigned int*)g,
                                     (AS3 unsigned int*)l, 16, 0, 0);
}

// ---------------- l2-normalize rows, fp32 -> fp8 e4m3, k-permuted ----------
// k-permutation (within each 64-elem block): dest byte q*16+h*8+b holds
// orig k = q*8 + h*32 + b.  Same permutation for f and c => dots invariant.
__global__ __launch_bounds__(256) void normalize_kernel(
        const float* __restrict__ feat, const float* __restrict__ cent,
        unsigned char* __restrict__ fN, unsigned char* __restrict__ cN) {
    const int w    = threadIdx.x >> 6;
    const int lane = threadIdx.x & 63;
    const int row  = blockIdx.x * 4 + w;      // 0 .. 12287

    const float* src = (row < N_ROWS) ? feat + (size_t)row * D_DIM
                                      : cent + (size_t)(row - N_ROWS) * D_DIM;
    unsigned char* dst = (row < N_ROWS) ? fN + (size_t)row * ROWB
                                        : cN + (size_t)(row - N_ROWS) * ROWB;

    const float* r = src + lane * 8;
    float4 v0 = *(const float4*)(r);
    float4 v1 = *(const float4*)(r + 4);
    float ss = v0.x*v0.x + v0.y*v0.y + v0.z*v0.z + v0.w*v0.w
             + v1.x*v1.x + v1.y*v1.y + v1.z*v1.z + v1.w*v1.w;
    #pragma unroll
    for (int off = 32; off; off >>= 1) ss += __shfl_xor(ss, off);
    const float sc = 1.0f / fmaxf(sqrtf(ss), 1e-12f);

    int p0 = __builtin_amdgcn_cvt_pk_fp8_f32(v0.x * sc, v0.y * sc, 0, false);
    p0     = __builtin_amdgcn_cvt_pk_fp8_f32(v0.z * sc, v0.w * sc, p0, true);
    int p1 = __builtin_amdgcn_cvt_pk_fp8_f32(v1.x * sc, v1.y * sc, 0, false);
    p1     = __builtin_amdgcn_cvt_pk_fp8_f32(v1.z * sc, v1.w * sc, p1, true);

    // lane handles orig k = lane*8..+8 -> kb=lane>>3, q=lane&3, h=(lane>>2)&1
    const int db = ((lane >> 3) << 6) + ((lane & 3) << 4) + (((lane >> 2) & 1) << 3);
    uint2 o; o.x = (unsigned)p0; o.y = (unsigned)p1;
    *(uint2*)(dst + db) = o;
}

// ---------------- pos_dot[i] = fN[i] . cN[labels[i]]  (fp8 inputs) ---------
__global__ __launch_bounds__(256) void posdot_kernel(
        const unsigned char* __restrict__ fN, const unsigned char* __restrict__ cN,
        const int* __restrict__ labels, float* __restrict__ pos) {
    const int w    = threadIdx.x >> 6;
    const int lane = threadIdx.x & 63;
    const int i    = blockIdx.x * 4 + w;
    const int lab  = labels[i];

    const uint2 a = *(const uint2*)(fN + (size_t)i   * ROWB + lane * 8);
    const uint2 b = *(const uint2*)(cN + (size_t)lab * ROWB + lane * 8);
    float s = 0.0f;
    // byte-select operand must be a LITERAL constant -> fully expanded
    s += __builtin_amdgcn_cvt_f32_fp8((int)a.x, 0) * __builtin_amdgcn_cvt_f32_fp8((int)b.x, 0);
    s += __builtin_amdgcn_cvt_f32_fp8((int)a.x, 1) * __builtin_amdgcn_cvt_f32_fp8((int)b.x, 1);
    s += __builtin_amdgcn_cvt_f32_fp8((int)a.x, 2) * __builtin_amdgcn_cvt_f32_fp8((int)b.x, 2);
    s += __builtin_amdgcn_cvt_f32_fp8((int)a.x, 3) * __builtin_amdgcn_cvt_f32_fp8((int)b.x, 3);
    s += __builtin_amdgcn_cvt_f32_fp8((int)a.y, 0) * __builtin_amdgcn_cvt_f32_fp8((int)b.y, 0);
    s += __builtin_amdgcn_cvt_f32_fp8((int)a.y, 1) * __builtin_amdgcn_cvt_f32_fp8((int)b.y, 1);
    s += __builtin_amdgcn_cvt_f32_fp8((int)a.y, 2) * __builtin_amdgcn_cvt_f32_fp8((int)b.y, 2);
    s += __builtin_amdgcn_cvt_f32_fp8((int)a.y, 3) * __builtin_amdgcn_cvt_f32_fp8((int)b.y, 3);
    #pragma unroll
    for (int off = 32; off; off >>= 1) s += __shfl_xor(s, off);
    if (lane == 0) pos[i] = s;
}

// ---------------- fused fp8 GEMM + masked softplus reduction ----------------
// IDENTICAL to R9's passing kernel (launch_bounds(512,4): VGPR 64, no spill,
// 2 blocks/CU) with ONE change: XCD-stripe block mapping. XCD k (= id&7,
// round-robin dispatch) owns col-tiles [k*8, k*8+8): per-XCD L2 footprint =
// 0.5 MB cN stripe + 2 MB fN = 2.5 MB < 4 MB -> staging L2-served.
__global__ __launch_bounds__(512, 4) void fused_loss_kernel(
        const unsigned char* __restrict__ fN, const unsigned char* __restrict__ cN,
        const int* __restrict__ labels, const float* __restrict__ pos,
        float* __restrict__ partialL, unsigned int* __restrict__ partialC) {
    __shared__ __align__(16) unsigned char As[2][BM * BKB];   // 32 KB
    __shared__ __align__(16) unsigned char Bs[2][BN * BKB];   // 16 KB

    const int tid  = threadIdx.x;
    const int w    = tid >> 6;        // wave 0..7
    const int lane = tid & 63;
    const int wm   = w >> 1;          // 0..3  (M quarter: rows wm*64..+63)
    const int wn   = w & 1;           // 0..1  (N half:   cols wn*64..+63)

    // XCD-stripe mapping (bijective: 1024 = 8 xcd * 16 by * 8 c8)
    const int id  = blockIdx.x;       // 0..1023
    const int xcd = id & 7;
    const int loc = id >> 3;          // 0..127
    const int by  = loc & 15;         // inner: A rows sweep while B fixed
    const int c8  = loc >> 4;         // 0..7
    const int rowBase = by * BM;
    const int colBase = (xcd * 8 + c8) * BN;

    const int lr = lane & 15;
    const int kq = lane >> 4;         // 0..3 = 16B seg (both kk halves)

    // staging: chunk = 16 rows x 64B; lane l -> row l>>2, LDS seg l&3,
    // fetching pre-swizzled global seg (l&3)^f(l>>2), f(x)=(x^(x>>2))&3
    const int gseg = ((lane & 3) ^ ((lane >> 2) & 3) ^ ((lane >> 4) & 3));
    const unsigned char* aG = fN + (size_t)(rowBase + w * 32 + (lane >> 2)) * ROWB + gseg * 16;
    const unsigned char* bG = cN + (size_t)(colBase + w * 16 + (lane >> 2)) * ROWB + gseg * 16;

#define STAGE(buf, t)                                                        \
    do {                                                                     \
        gload_lds16(aG + (t) * BKB,             &As[buf][(w * 32) * BKB]);   \
        gload_lds16(aG + (t) * BKB + 16 * ROWB, &As[buf][(w * 32 + 16) * BKB]); \
        gload_lds16(bG + (t) * BKB,             &Bs[buf][(w * 16) * BKB]);   \
    } while (0)

    // read: lane wants global seg kq at row (16-aligned base + lr):
    // LDS seg = kq ^ f(lr);   b128 -> [kk=0 | kk=1] halves
    const int segrd = (lane ^ (lane >> 2) ^ (lane >> 4)) & 3;
    const int loff  = lr * BKB + segrd * 16;     // per-lane offset in tile

    f32x4 acc[4][4] = {};

    // prologue: tiles 0,1 in flight (6 loads/wave)
    STAGE(0, 0);
    STAGE(1, 1);
    asm volatile("s_waitcnt vmcnt(3)" ::: "memory");
    __builtin_amdgcn_s_barrier();

    #pragma unroll
    for (int t = 0; t < NKT; ++t) {
        const int cur = t & 1;

        i64x2 af[4], bb[4];
        #pragma unroll
        for (int m = 0; m < 4; ++m)
            af[m] = *(const i64x2*)&As[cur][(wm * 64 + m * 16) * BKB + loff];
        #pragma unroll
        for (int n = 0; n < 4; ++n)
            bb[n] = *(const i64x2*)&Bs[cur][(wn * 64 + n * 16) * BKB + loff];
        asm volatile("s_waitcnt lgkmcnt(0)" ::: "memory");
        __builtin_amdgcn_sched_barrier(0);
        __builtin_amdgcn_s_barrier();            // all waves done with buf[cur]

        if (t + 2 < NKT) STAGE(cur, t + 2);      // overwrite freed buffer

        #pragma unroll
        for (int kk = 0; kk < 2; ++kk)
            #pragma unroll
            for (int m = 0; m < 4; ++m)
                #pragma unroll
                for (int n = 0; n < 4; ++n)
                    acc[m][n] = __builtin_amdgcn_mfma_f32_16x16x32_fp8_fp8(
                                    af[m][kk], bb[n][kk], acc[m][n], 0, 0, 0);

        if (t < NKT - 1) {
            if (t < NKT - 2) asm volatile("s_waitcnt vmcnt(3)" ::: "memory");
            else             asm volatile("s_waitcnt vmcnt(0)" ::: "memory");
            __builtin_amdgcn_s_barrier();        // next tile landed chip-wide
        }
    }
#undef STAGE

    // ---- epilogue: x = S_ij - pos[i]; mask j != label[i]; softplus; sum ----
    float lsum = 0.0f;
    unsigned cnt = 0;
    #pragma unroll
    for (int m = 0; m < 4; ++m) {
        #pragma unroll
        for (int j = 0; j < 4; ++j) {
            const int gi = rowBase + wm * 64 + m * 16 + kq * 4 + j;
            const float p = pos[gi];
            const int lab = labels[gi];
            #pragma unroll
            for (int n = 0; n < 4; ++n) {
                const int gj = colBase + wn * 64 + n * 16 + lr;
                const float x = acc[m][n][j] - p;
                if (gj != lab) {
                    const float l = __logf(1.0f + __expf(x));   // softplus
                    if (l > 0.0f) { lsum += l; cnt++; }
                }
            }
        }
    }
    #pragma unroll
    for (int off = 32; off; off >>= 1) {
        lsum += __shfl_xor(lsum, off);
        cnt  += __shfl_xor(cnt,  off);
    }

    __syncthreads();                        // safe to reuse LDS
    float*    s_sum = (float*)&As[0][0];
    unsigned* s_cnt = (unsigned*)&As[0][64];
    if (lane == 0) { s_sum[w] = lsum; s_cnt[w] = cnt; }
    __syncthreads();
    if (tid == 0) {
        float    L = 0.0f;
        unsigned C = 0;
        #pragma unroll
        for (int i = 0; i < 8; ++i) { L += s_sum[i]; C += s_cnt[i]; }
        partialL[id] = L;
        partialC[id] = C;
    }
}

// ---------------- finalize: reduce 1024 per-block partials ----------------
__global__ __launch_bounds__(256) void finalize_kernel(
        const float* __restrict__ partialL, const unsigned int* __restrict__ partialC,
        float* __restrict__ out) {
    __shared__ float    s_sum[4];
    __shared__ unsigned s_cnt[4];
    const int w    = threadIdx.x >> 6;
    const int lane = threadIdx.x & 63;

    float s = 0.0f; unsigned c = 0;
    for (int i = threadIdx.x; i < NBLK; i += 256) { s += partialL[i]; c += partialC[i]; }
    #pragma unroll
    for (int off = 32; off; off >>= 1) {
        s += __shfl_xor(s, off);
        c += __shfl_xor(c, off);
    }
    if (lane == 0) { s_sum[w] = s; s_cnt[w] = c; }
    __syncthreads();
    if (threadIdx.x == 0) {
        const float    l = s_sum[0] + s_sum[1] + s_sum[2] + s_sum[3];
        const unsigned n = s_cnt[0] + s_cnt[1] + s_cnt[2] + s_cnt[3];
        out[0] = (n > 0u) ? l / (float)n : l;
    }
}

extern "C" void kernel_launch(void* const* d_in, const int* in_sizes, int n_in,
                              void* d_out, int out_size, void* d_ws, size_t ws_size,
                              hipStream_t stream) {
    const float* features = (const float*)d_in[0];   // [4096, 512]
    const float* centers  = (const float*)d_in[1];   // [8192, 512]
    const int*   labels   = (const int*)d_in[2];     // [4096]
    float* out = (float*)d_out;

    char* ws = (char*)d_ws;
    unsigned char* fN  = (unsigned char*)ws;                          // 2 MB
    unsigned char* cN  = (unsigned char*)(ws + (2u << 20));           // 4 MB
    float*         pos = (float*)(ws + (6u << 20));                   // 16 KB
    float*         partialL = (float*)(ws + (6u << 20) + (1u << 16));           // 4 KB
    unsigned int*  partialC = (unsigned int*)(ws + (6u << 20) + (1u << 16) + (1u << 14));

    normalize_kernel<<<(N_ROWS + C_ROWS) / 4, 256, 0, stream>>>(features, centers, fN, cN);
    posdot_kernel<<<N_ROWS / 4, 256, 0, stream>>>(fN, cN, labels, pos);

    fused_loss_kernel<<<NBLK, 512, 0, stream>>>(fN, cN, labels, pos, partialL, partialC);

    finalize_kernel<<<1, 256, 0, stream>>>(partialL, partialC, out);
}

// Round 12
// 52.879 us; speedup vs baseline: 4.5458x; 1.0000x over previous
//
#include <hip/hip_runtime.h>

#define N_ROWS 4096
#define D_DIM  512
#define ROWB   512              // bytes per i8 row
#define C_ROWS 8192
#define BM 256
#define BN 128
#define BKB 64                  // K-tile bytes = 64 i8 elems
#define NKT 8                   // 512 / 64
#define GXf (C_ROWS / BN)       // 64
#define GYf (N_ROWS / BM)       // 16
#define NBLK (GXf * GYf)        // 1024

typedef __attribute__((ext_vector_type(4))) int  i32x4;    // MFMA i8 frag/acc
typedef __attribute__((ext_vector_type(4))) float f32x4;

#define AS1 __attribute__((address_space(1)))
#define AS3 __attribute__((address_space(3)))

__device__ __forceinline__ void gload_lds16(const void* g, void* l) {
    __builtin_amdgcn_global_load_lds((const AS1 unsigned int*)g,
                                     (AS3 unsigned int*)l, 16, 0, 0);
}

// ---------------- l2-normalize rows, fp32 -> i8 (q = round(127 x̂)) --------
// plain row-major layout (i8 16x16x64 frag = 16 CONTIGUOUS k per lane).
__global__ __launch_bounds__(256) void normalize_kernel(
        const float* __restrict__ feat, const float* __restrict__ cent,
        unsigned char* __restrict__ fN, unsigned char* __restrict__ cN) {
    const int w    = threadIdx.x >> 6;
    const int lane = threadIdx.x & 63;
    const int row  = blockIdx.x * 4 + w;      // 0 .. 12287

    const float* src = (row < N_ROWS) ? feat + (size_t)row * D_DIM
                                      : cent + (size_t)(row - N_ROWS) * D_DIM;
    unsigned char* dst = (row < N_ROWS) ? fN + (size_t)row * ROWB
                                        : cN + (size_t)(row - N_ROWS) * ROWB;

    const float* r = src + lane * 8;
    float4 v0 = *(const float4*)(r);
    float4 v1 = *(const float4*)(r + 4);
    float ss = v0.x*v0.x + v0.y*v0.y + v0.z*v0.z + v0.w*v0.w
             + v1.x*v1.x + v1.y*v1.y + v1.z*v1.z + v1.w*v1.w;
    #pragma unroll
    for (int off = 32; off; off >>= 1) ss += __shfl_xor(ss, off);
    const float sc = 127.0f / fmaxf(sqrtf(ss), 1e-12f);

    int q0 = __float2int_rn(v0.x * sc), q1 = __float2int_rn(v0.y * sc);
    int q2 = __float2int_rn(v0.z * sc), q3 = __float2int_rn(v0.w * sc);
    int q4 = __float2int_rn(v1.x * sc), q5 = __float2int_rn(v1.y * sc);
    int q6 = __float2int_rn(v1.z * sc), q7 = __float2int_rn(v1.w * sc);

    uint2 o;
    o.x = (q0 & 0xFF) | ((q1 & 0xFF) << 8) | ((q2 & 0xFF) << 16) | ((q3 & 0xFF) << 24);
    o.y = (q4 & 0xFF) | ((q5 & 0xFF) << 8) | ((q6 & 0xFF) << 16) | ((q7 & 0xFF) << 24);
    *(uint2*)(dst + lane * 8) = o;
}

// ------------- pos_int[i] = fQ[i] . cQ[labels[i]]  (exact in fp32) ---------
__global__ __launch_bounds__(256) void posdot_kernel(
        const unsigned char* __restrict__ fN, const unsigned char* __restrict__ cN,
        const int* __restrict__ labels, float* __restrict__ pos) {
    const int w    = threadIdx.x >> 6;
    const int lane = threadIdx.x & 63;
    const int i    = blockIdx.x * 4 + w;
    const int lab  = labels[i];

    const uint2 a = *(const uint2*)(fN + (size_t)i   * ROWB + lane * 8);
    const uint2 b = *(const uint2*)(cN + (size_t)lab * ROWB + lane * 8);
    int s = 0;
    #pragma unroll
    for (int j = 0; j < 4; ++j) {
        s += (int)(signed char)((a.x >> (8 * j)) & 0xFF) *
             (int)(signed char)((b.x >> (8 * j)) & 0xFF);
        s += (int)(signed char)((a.y >> (8 * j)) & 0xFF) *
             (int)(signed char)((b.y >> (8 * j)) & 0xFF);
    }
    #pragma unroll
    for (int off = 32; off; off >>= 1) s += __shfl_xor(s, off);
    if (lane == 0) pos[i] = (float)s;    // |s| <= 8.3M < 2^24: exact
}

// ---------------- fused i8 GEMM + masked softplus reduction ----------------
// Structure identical to R11 (256x128 tile, BK=64B, 8 waves 4Mx2N, double
// buffer, counted vmcnt(3), 2 barriers/K-tile, XCD stripe, seg swizzle).
// MFMA: mfma_i32_16x16x64_i8 -- 2x the fp8/bf16 rate; frag = one b128 of
// 16 contiguous k per lane (plain storage, swizzled LDS segs only).
__global__ __launch_bounds__(512, 4) void fused_loss_kernel(
        const unsigned char* __restrict__ fN, const unsigned char* __restrict__ cN,
        const int* __restrict__ labels, const float* __restrict__ pos,
        float* __restrict__ partialL, unsigned int* __restrict__ partialC) {
    __shared__ __align__(16) unsigned char As[2][BM * BKB];   // 32 KB
    __shared__ __align__(16) unsigned char Bs[2][BN * BKB];   // 16 KB

    const int tid  = threadIdx.x;
    const int w    = tid >> 6;        // wave 0..7
    const int lane = tid & 63;
    const int wm   = w >> 1;          // 0..3  (M quarter: rows wm*64..+63)
    const int wn   = w & 1;           // 0..1  (N half:   cols wn*64..+63)

    // XCD-stripe mapping (bijective: 1024 = 8 xcd * 16 by * 8 c8)
    const int id  = blockIdx.x;       // 0..1023
    const int xcd = id & 7;
    const int loc = id >> 3;          // 0..127
    const int by  = loc & 15;         // inner: A rows sweep while B fixed
    const int c8  = loc >> 4;         // 0..7
    const int rowBase = by * BM;
    const int colBase = (xcd * 8 + c8) * BN;

    const int lr = lane & 15;
    const int kq = lane >> 4;         // 0..3 = 16B k-seg

    // staging: chunk = 16 rows x 64B; lane l -> row l>>2, LDS seg l&3,
    // fetching pre-swizzled global seg (l&3)^f(l>>2), f(x)=(x^(x>>2))&3
    const int gseg = ((lane & 3) ^ ((lane >> 2) & 3) ^ ((lane >> 4) & 3));
    const unsigned char* aG = fN + (size_t)(rowBase + w * 32 + (lane >> 2)) * ROWB + gseg * 16;
    const unsigned char* bG = cN + (size_t)(colBase + w * 16 + (lane >> 2)) * ROWB + gseg * 16;

#define STAGE(buf, t)                                                        \
    do {                                                                     \
        gload_lds16(aG + (t) * BKB,             &As[buf][(w * 32) * BKB]);   \
        gload_lds16(aG + (t) * BKB + 16 * ROWB, &As[buf][(w * 32 + 16) * BKB]); \
        gload_lds16(bG + (t) * BKB,             &Bs[buf][(w * 16) * BKB]);   \
    } while (0)

    // read: lane wants global seg kq (16 contiguous k) at row base+lr:
    // LDS seg = kq ^ f(lr)
    const int segrd = (lane ^ (lane >> 2) ^ (lane >> 4)) & 3;
    const int loff  = lr * BKB + segrd * 16;     // per-lane offset in tile

    i32x4 acc[4][4] = {};

    // prologue: tiles 0,1 in flight (6 loads/wave)
    STAGE(0, 0);
    STAGE(1, 1);
    asm volatile("s_waitcnt vmcnt(3)" ::: "memory");
    __builtin_amdgcn_s_barrier();

    #pragma unroll
    for (int t = 0; t < NKT; ++t) {
        const int cur = t & 1;

        i32x4 af[4], bb[4];
        #pragma unroll
        for (int m = 0; m < 4; ++m)
            af[m] = *(const i32x4*)&As[cur][(wm * 64 + m * 16) * BKB + loff];
        #pragma unroll
        for (int n = 0; n < 4; ++n)
            bb[n] = *(const i32x4*)&Bs[cur][(wn * 64 + n * 16) * BKB + loff];
        asm volatile("s_waitcnt lgkmcnt(0)" ::: "memory");
        __builtin_amdgcn_sched_barrier(0);
        __builtin_amdgcn_s_barrier();            // all waves done with buf[cur]

        if (t + 2 < NKT) STAGE(cur, t + 2);      // overwrite freed buffer

        #pragma unroll
        for (int m = 0; m < 4; ++m)
            #pragma unroll
            for (int n = 0; n < 4; ++n)
                acc[m][n] = __builtin_amdgcn_mfma_i32_16x16x64_i8(
                                af[m], bb[n], acc[m][n], 0, 0, 0);

        if (t < NKT - 1) {
            if (t < NKT - 2) asm volatile("s_waitcnt vmcnt(3)" ::: "memory");
            else             asm volatile("s_waitcnt vmcnt(0)" ::: "memory");
            __builtin_amdgcn_s_barrier();        // next tile landed chip-wide
        }
    }
#undef STAGE

    // ---- epilogue: x = (S_int - pos_int)/127^2; mask; softplus; sum ----
    const float inv = 1.0f / 16129.0f;
    float lsum = 0.0f;
    unsigned cnt = 0;
    #pragma unroll
    for (int m = 0; m < 4; ++m) {
        #pragma unroll
        for (int j = 0; j < 4; ++j) {
            const int gi = rowBase + wm * 64 + m * 16 + kq * 4 + j;
            const float p = pos[gi];
            const int lab = labels[gi];
            #pragma unroll
            for (int n = 0; n < 4; ++n) {
                const int gj = colBase + wn * 64 + n * 16 + lr;
                const float x = ((float)acc[m][n][j] - p) * inv;
                if (gj != lab) {
                    const float l = __logf(1.0f + __expf(x));   // softplus
                    if (l > 0.0f) { lsum += l; cnt++; }
                }
            }
        }
    }
    #pragma unroll
    for (int off = 32; off; off >>= 1) {
        lsum += __shfl_xor(lsum, off);
        cnt  += __shfl_xor(cnt,  off);
    }

    __syncthreads();                        // safe to reuse LDS
    float*    s_sum = (float*)&As[0][0];
    unsigned* s_cnt = (unsigned*)&As[0][64];
    if (lane == 0) { s_sum[w] = lsum; s_cnt[w] = cnt; }
    __syncthreads();
    if (tid == 0) {
        float    L = 0.0f;
        unsigned C = 0;
        #pragma unroll
        for (int i = 0; i < 8; ++i) { L += s_sum[i]; C += s_cnt[i]; }
        partialL[id] = L;
        partialC[id] = C;
    }
}

// ---------------- finalize: reduce 1024 per-block partials ----------------
__global__ __launch_bounds__(256) void finalize_kernel(
        const float* __restrict__ partialL, const unsigned int* __restrict__ partialC,
        float* __restrict__ out) {
    __shared__ float    s_sum[4];
    __shared__ unsigned s_cnt[4];
    const int w    = threadIdx.x >> 6;
    const int lane = threadIdx.x & 63;

    float s = 0.0f; unsigned c = 0;
    for (int i = threadIdx.x; i < NBLK; i += 256) { s += partialL[i]; c += partialC[i]; }
    #pragma unroll
    for (int off = 32; off; off >>= 1) {
        s += __shfl_xor(s, off);
        c += __shfl_xor(c, off);
    }
    if (lane == 0) { s_sum[w] = s; s_cnt[w] = c; }
    __syncthreads();
    if (threadIdx.x == 0) {
        const float    l = s_sum[0] + s_sum[1] + s_sum[2] + s_sum[3];
        const unsigned n = s_cnt[0] + s_cnt[1] + s_cnt[2] + s_cnt[3];
        out[0] = (n > 0u) ? l / (float)n : l;
    }
}

extern "C" void kernel_launch(void* const* d_in, const int* in_sizes, int n_in,
                              void* d_out, int out_size, void* d_ws, size_t ws_size,
                              hipStream_t stream) {
    const float* features = (const float*)d_in[0];   // [4096, 512]
    const float* centers  = (const float*)d_in[1];   // [8192, 512]
    const int*   labels   = (const int*)d_in[2];     // [4096]
    float* out = (float*)d_out;

    char* ws = (char*)d_ws;
    unsigned char* fN  = (unsigned char*)ws;                          // 2 MB
    unsigned char* cN  = (unsigned char*)(ws + (2u << 20));           // 4 MB
    float*         pos = (float*)(ws + (6u << 20));                   // 16 KB
    float*         partialL = (float*)(ws + (6u << 20) + (1u << 16));           // 4 KB
    unsigned int*  partialC = (unsigned int*)(ws + (6u << 20) + (1u << 16) + (1u << 14));

    normalize_kernel<<<(N_ROWS + C_ROWS) / 4, 256, 0, stream>>>(features, centers, fN, cN);
    posdot_kernel<<<N_ROWS / 4, 256, 0, stream>>>(fN, cN, labels, pos);

    fused_loss_kernel<<<NBLK, 512, 0, stream>>>(fN, cN, labels, pos, partialL, partialC);

    finalize_kernel<<<1, 256, 0, stream>>>(partialL, partialC, out);
}

// Round 13
// 47.909 us; speedup vs baseline: 5.0174x; 1.1037x over previous
//
#include <hip/hip_runtime.h>

#define N_ROWS 4096
#define D_DIM  512
#define ROWB   512              // bytes per i8 row
#define C_ROWS 8192
#define BM 256
#define BN 128
#define BKB 64                  // K-tile bytes = 64 i8 elems
#define NKT 8                   // 512 / 64
#define GXf (C_ROWS / BN)       // 64
#define GYf (N_ROWS / BM)       // 16
#define NBLK (GXf * GYf)        // 1024
#define NVALID 33550336.0f      // 4096 * 8191 (num_valid is provably constant)

typedef __attribute__((ext_vector_type(4))) int  i32x4;    // MFMA i8 frag/acc

#define AS1 __attribute__((address_space(1)))
#define AS3 __attribute__((address_space(3)))

__device__ __forceinline__ void gload_lds16(const void* g, void* l) {
    __builtin_amdgcn_global_load_lds((const AS1 unsigned int*)g,
                                     (AS3 unsigned int*)l, 16, 0, 0);
}

// ---------------- l2-normalize rows, fp32 -> i8 (q = round(127 x̂)) --------
__global__ __launch_bounds__(256) void normalize_kernel(
        const float* __restrict__ feat, const float* __restrict__ cent,
        unsigned char* __restrict__ fN, unsigned char* __restrict__ cN) {
    const int w    = threadIdx.x >> 6;
    const int lane = threadIdx.x & 63;
    const int row  = blockIdx.x * 4 + w;      // 0 .. 12287

    const float* src = (row < N_ROWS) ? feat + (size_t)row * D_DIM
                                      : cent + (size_t)(row - N_ROWS) * D_DIM;
    unsigned char* dst = (row < N_ROWS) ? fN + (size_t)row * ROWB
                                        : cN + (size_t)(row - N_ROWS) * ROWB;

    const float* r = src + lane * 8;
    float4 v0 = *(const float4*)(r);
    float4 v1 = *(const float4*)(r + 4);
    float ss = v0.x*v0.x + v0.y*v0.y + v0.z*v0.z + v0.w*v0.w
             + v1.x*v1.x + v1.y*v1.y + v1.z*v1.z + v1.w*v1.w;
    #pragma unroll
    for (int off = 32; off; off >>= 1) ss += __shfl_xor(ss, off);
    const float sc = 127.0f / fmaxf(sqrtf(ss), 1e-12f);

    int q0 = __float2int_rn(v0.x * sc), q1 = __float2int_rn(v0.y * sc);
    int q2 = __float2int_rn(v0.z * sc), q3 = __float2int_rn(v0.w * sc);
    int q4 = __float2int_rn(v1.x * sc), q5 = __float2int_rn(v1.y * sc);
    int q6 = __float2int_rn(v1.z * sc), q7 = __float2int_rn(v1.w * sc);

    uint2 o;
    o.x = (q0 & 0xFF) | ((q1 & 0xFF) << 8) | ((q2 & 0xFF) << 16) | ((q3 & 0xFF) << 24);
    o.y = (q4 & 0xFF) | ((q5 & 0xFF) << 8) | ((q6 & 0xFF) << 16) | ((q7 & 0xFF) << 24);
    *(uint2*)(dst + lane * 8) = o;
}

// ------------- pos_int[i] = fQ[i] . cQ[labels[i]]  (exact in fp32) ---------
__global__ __launch_bounds__(256) void posdot_kernel(
        const unsigned char* __restrict__ fN, const unsigned char* __restrict__ cN,
        const int* __restrict__ labels, float* __restrict__ pos) {
    const int w    = threadIdx.x >> 6;
    const int lane = threadIdx.x & 63;
    const int i    = blockIdx.x * 4 + w;
    const int lab  = labels[i];

    const uint2 a = *(const uint2*)(fN + (size_t)i   * ROWB + lane * 8);
    const uint2 b = *(const uint2*)(cN + (size_t)lab * ROWB + lane * 8);
    int s = 0;
    #pragma unroll
    for (int j = 0; j < 4; ++j) {
        s += (int)(signed char)((a.x >> (8 * j)) & 0xFF) *
             (int)(signed char)((b.x >> (8 * j)) & 0xFF);
        s += (int)(signed char)((a.y >> (8 * j)) & 0xFF) *
             (int)(signed char)((b.y >> (8 * j)) & 0xFF);
    }
    #pragma unroll
    for (int off = 32; off; off >>= 1) s += __shfl_xor(s, off);
    if (lane == 0) pos[i] = (float)s;    // |s| <= 8.3M < 2^24: exact
}

// ---------------- fused i8 GEMM + masked softplus reduction ----------------
// R12 structure with the latency-serialized loop replaced by a TRIPLE-
// buffered single-barrier pipeline:
//  - 3 LDS buffers: buffer (t+2)%3 was last read in iter t-1, and the iter-t
//    barrier publishes that all waves finished those reads -> no release
//    barrier, no lgkmcnt(0), no sched_barrier.
//  - per iter: vmcnt(6) waits ONLY tile t (its 6 loads issued 2 iters ago,
//    fully landed) -> zero exposed load latency.  ONE barrier per iter.
//  - ds_read latency hides under MFMA via compiler-emitted counted lgkmcnt.
__global__ __launch_bounds__(512, 4) void fused_loss_kernel(
        const unsigned char* __restrict__ fN, const unsigned char* __restrict__ cN,
        const int* __restrict__ labels, const float* __restrict__ pos,
        float* __restrict__ partialL) {
    __shared__ __align__(16) unsigned char As[3][BM * BKB];   // 48 KB
    __shared__ __align__(16) unsigned char Bs[3][BN * BKB];   // 24 KB

    const int tid  = threadIdx.x;
    const int w    = tid >> 6;        // wave 0..7
    const int lane = tid & 63;
    const int wm   = w >> 1;          // 0..3  (M quarter: rows wm*64..+63)
    const int wn   = w & 1;           // 0..1  (N half:   cols wn*64..+63)

    // XCD-stripe mapping (bijective: 1024 = 8 xcd * 16 by * 8 c8)
    const int id  = blockIdx.x;       // 0..1023
    const int xcd = id & 7;
    const int loc = id >> 3;          // 0..127
    const int by  = loc & 15;         // inner: A rows sweep while B fixed
    const int c8  = loc >> 4;         // 0..7
    const int rowBase = by * BM;
    const int colBase = (xcd * 8 + c8) * BN;

    const int lr = lane & 15;
    const int kq = lane >> 4;         // 0..3 = 16B k-seg

    // staging: chunk = 16 rows x 64B; lane l -> row l>>2, LDS seg l&3,
    // fetching pre-swizzled global seg (l&3)^f(l>>2), f(x)=(x^(x>>2))&3
    const int gseg = ((lane & 3) ^ ((lane >> 2) & 3) ^ ((lane >> 4) & 3));
    const unsigned char* aG = fN + (size_t)(rowBase + w * 32 + (lane >> 2)) * ROWB + gseg * 16;
    const unsigned char* bG = cN + (size_t)(colBase + w * 16 + (lane >> 2)) * ROWB + gseg * 16;

#define STAGE(buf, t)                                                        \
    do {                                                                     \
        gload_lds16(aG + (t) * BKB,             &As[buf][(w * 32) * BKB]);   \
        gload_lds16(aG + (t) * BKB + 16 * ROWB, &As[buf][(w * 32 + 16) * BKB]); \
        gload_lds16(bG + (t) * BKB,             &Bs[buf][(w * 16) * BKB]);   \
    } while (0)

    // read: lane wants global seg kq (16 contiguous k) at row base+lr:
    // LDS seg = kq ^ f(lr)
    const int segrd = (lane ^ (lane >> 2) ^ (lane >> 4)) & 3;
    const int loff  = lr * BKB + segrd * 16;     // per-lane offset in tile

    i32x4 acc[4][4] = {};

    // prologue: tiles 0,1 in flight (12 loads/wave)
    STAGE(0, 0);
    STAGE(1, 1);

    #pragma unroll
    for (int t = 0; t < NKT; ++t) {
        const int cur = t % 3;
        // tile t's 6 loads are the oldest outstanding -> vmcnt(6) retires
        // exactly them (tile t+1's 6 stay in flight).  Last iter: drain.
        if (t < NKT - 1) asm volatile("s_waitcnt vmcnt(6)" ::: "memory");
        else             asm volatile("s_waitcnt vmcnt(0)" ::: "memory");
        __builtin_amdgcn_s_barrier();    // publishes tile t's LDS + proves all
                                         // waves done reading buf[(t+2)%3]
        if (t + 2 < NKT) STAGE((t + 2) % 3, t + 2);

        i32x4 af[4], bb[4];
        #pragma unroll
        for (int m = 0; m < 4; ++m)
            af[m] = *(const i32x4*)&As[cur][(wm * 64 + m * 16) * BKB + loff];
        #pragma unroll
        for (int n = 0; n < 4; ++n)
            bb[n] = *(const i32x4*)&Bs[cur][(wn * 64 + n * 16) * BKB + loff];

        // compiler emits counted lgkmcnt between reads and consuming MFMAs:
        // ds_read latency overlaps the first MFMAs.
        #pragma unroll
        for (int m = 0; m < 4; ++m)
            #pragma unroll
            for (int n = 0; n < 4; ++n)
                acc[m][n] = __builtin_amdgcn_mfma_i32_16x16x64_i8(
                                af[m], bb[n], acc[m][n], 0, 0, 0);
    }
#undef STAGE

    // ---- epilogue: x = (S_int - pos_int)/127^2; mask j!=label; softplus ----
    // (softplus(x) > 0 always for |x|<=2.2 -> num_valid == N*(C-1), constant)
    const float inv = 1.0f / 16129.0f;
    float lsum = 0.0f;
    #pragma unroll
    for (int m = 0; m < 4; ++m) {
        #pragma unroll
        for (int j = 0; j < 4; ++j) {
            const int gi = rowBase + wm * 64 + m * 16 + kq * 4 + j;
            const float p = pos[gi];
            const int lab = labels[gi];
            #pragma unroll
            for (int n = 0; n < 4; ++n) {
                const int gj = colBase + wn * 64 + n * 16 + lr;
                const float x = ((float)acc[m][n][j] - p) * inv;
                const float l = __logf(1.0f + __expf(x));   // softplus > 0
                lsum += (gj != lab) ? l : 0.0f;
            }
        }
    }
    #pragma unroll
    for (int off = 32; off; off >>= 1) lsum += __shfl_xor(lsum, off);

    __syncthreads();                        // safe to reuse LDS
    float* s_sum = (float*)&As[0][0];
    if (lane == 0) s_sum[w] = lsum;
    __syncthreads();
    if (tid == 0) {
        float L = 0.0f;
        #pragma unroll
        for (int i = 0; i < 8; ++i) L += s_sum[i];
        partialL[id] = L;
    }
}

// ---------------- finalize: reduce 1024 per-block partials ----------------
__global__ __launch_bounds__(256) void finalize_kernel(
        const float* __restrict__ partialL, float* __restrict__ out) {
    __shared__ float s_sum[4];
    const int w    = threadIdx.x >> 6;
    const int lane = threadIdx.x & 63;

    float s = 0.0f;
    for (int i = threadIdx.x; i < NBLK; i += 256) s += partialL[i];
    #pragma unroll
    for (int off = 32; off; off >>= 1) s += __shfl_xor(s, off);
    if (lane == 0) s_sum[w] = s;
    __syncthreads();
    if (threadIdx.x == 0)
        out[0] = (s_sum[0] + s_sum[1] + s_sum[2] + s_sum[3]) / NVALID;
}

extern "C" void kernel_launch(void* const* d_in, const int* in_sizes, int n_in,
                              void* d_out, int out_size, void* d_ws, size_t ws_size,
                              hipStream_t stream) {
    const float* features = (const float*)d_in[0];   // [4096, 512]
    const float* centers  = (const float*)d_in[1];   // [8192, 512]
    const int*   labels   = (const int*)d_in[2];     // [4096]
    float* out = (float*)d_out;

    char* ws = (char*)d_ws;
    unsigned char* fN  = (unsigned char*)ws;                          // 2 MB
    unsigned char* cN  = (unsigned char*)(ws + (2u << 20));           // 4 MB
    float*         pos = (float*)(ws + (6u << 20));                   // 16 KB
    float*         partialL = (float*)(ws + (6u << 20) + (1u << 16)); // 4 KB

    normalize_kernel<<<(N_ROWS + C_ROWS) / 4, 256, 0, stream>>>(features, centers, fN, cN);
    posdot_kernel<<<N_ROWS / 4, 256, 0, stream>>>(fN, cN, labels, pos);

    fused_loss_kernel<<<NBLK, 512, 0, stream>>>(fN, cN, labels, pos, partialL);

    finalize_kernel<<<1, 256, 0, stream>>>(partialL, out);
}

// Round 15
// 45.968 us; speedup vs baseline: 5.2292x; 1.0422x over previous
//
#include <hip/hip_runtime.h>

#define N_ROWS 4096
#define D_DIM  512
#define ROWB   512              // bytes per i8 row
#define C_ROWS 8192
#define BM 256
#define BN 128
#define BKB 64                  // K-tile bytes = 64 i8 elems
#define NKT 8                   // 512 / 64
#define GXf (C_ROWS / BN)       // 64
#define GYf (N_ROWS / BM)       // 16
#define NBLK (GXf * GYf)        // 1024
#define NVALID 33550336.0f      // 4096 * 8191 (num_valid is provably constant)

typedef __attribute__((ext_vector_type(4))) int  i32x4;    // MFMA i8 frag/acc

#define AS1 __attribute__((address_space(1)))
#define AS3 __attribute__((address_space(3)))

__device__ __forceinline__ void gload_lds16(const void* g, void* l) {
    __builtin_amdgcn_global_load_lds((const AS1 unsigned int*)g,
                                     (AS3 unsigned int*)l, 16, 0, 0);
}

// ---------------- l2-normalize rows, fp32 -> i8 (q = round(127 x̂)) --------
__global__ __launch_bounds__(256) void normalize_kernel(
        const float* __restrict__ feat, const float* __restrict__ cent,
        unsigned char* __restrict__ fN, unsigned char* __restrict__ cN) {
    const int w    = threadIdx.x >> 6;
    const int lane = threadIdx.x & 63;
    const int row  = blockIdx.x * 4 + w;      // 0 .. 12287

    const float* src = (row < N_ROWS) ? feat + (size_t)row * D_DIM
                                      : cent + (size_t)(row - N_ROWS) * D_DIM;
    unsigned char* dst = (row < N_ROWS) ? fN + (size_t)row * ROWB
                                        : cN + (size_t)(row - N_ROWS) * ROWB;

    const float* r = src + lane * 8;
    float4 v0 = *(const float4*)(r);
    float4 v1 = *(const float4*)(r + 4);
    float ss = v0.x*v0.x + v0.y*v0.y + v0.z*v0.z + v0.w*v0.w
             + v1.x*v1.x + v1.y*v1.y + v1.z*v1.z + v1.w*v1.w;
    #pragma unroll
    for (int off = 32; off; off >>= 1) ss += __shfl_xor(ss, off);
    const float sc = 127.0f / fmaxf(sqrtf(ss), 1e-12f);

    int q0 = __float2int_rn(v0.x * sc), q1 = __float2int_rn(v0.y * sc);
    int q2 = __float2int_rn(v0.z * sc), q3 = __float2int_rn(v0.w * sc);
    int q4 = __float2int_rn(v1.x * sc), q5 = __float2int_rn(v1.y * sc);
    int q6 = __float2int_rn(v1.z * sc), q7 = __float2int_rn(v1.w * sc);

    uint2 o;
    o.x = (q0 & 0xFF) | ((q1 & 0xFF) << 8) | ((q2 & 0xFF) << 16) | ((q3 & 0xFF) << 24);
    o.y = (q4 & 0xFF) | ((q5 & 0xFF) << 8) | ((q6 & 0xFF) << 16) | ((q7 & 0xFF) << 24);
    *(uint2*)(dst + lane * 8) = o;
}

// ------------- pos_int[i] = fQ[i] . cQ[labels[i]]  (exact in fp32) ---------
__global__ __launch_bounds__(256) void posdot_kernel(
        const unsigned char* __restrict__ fN, const unsigned char* __restrict__ cN,
        const int* __restrict__ labels, float* __restrict__ pos) {
    const int w    = threadIdx.x >> 6;
    const int lane = threadIdx.x & 63;
    const int i    = blockIdx.x * 4 + w;
    const int lab  = labels[i];

    const uint2 a = *(const uint2*)(fN + (size_t)i   * ROWB + lane * 8);
    const uint2 b = *(const uint2*)(cN + (size_t)lab * ROWB + lane * 8);
    int s = 0;
    #pragma unroll
    for (int j = 0; j < 4; ++j) {
        s += (int)(signed char)((a.x >> (8 * j)) & 0xFF) *
             (int)(signed char)((b.x >> (8 * j)) & 0xFF);
        s += (int)(signed char)((a.y >> (8 * j)) & 0xFF) *
             (int)(signed char)((b.y >> (8 * j)) & 0xFF);
    }
    #pragma unroll
    for (int off = 32; off; off >>= 1) s += __shfl_xor(s, off);
    if (lane == 0) pos[i] = (float)s;    // |s| <= 8.3M < 2^24: exact
}

// ---------------- fused i8 GEMM + masked softplus reduction ----------------
// R13 triple-buffer single-barrier pipeline with the vmcnt RACE FIX:
// STAGE issues 3 loads/wave, so at iter t the per-wave outstanding queue is
// [tile t: 3, tile t+1: 3]; vmcnt(3) retires exactly tile t (R13's vmcnt(6)
// was a no-op -- correct only by timing).  Epilogue: softplus in exp2-domain,
// final ln2 folded into finalize.
__global__ __launch_bounds__(512, 4) void fused_loss_kernel(
        const unsigned char* __restrict__ fN, const unsigned char* __restrict__ cN,
        const int* __restrict__ labels, const float* __restrict__ pos,
        float* __restrict__ partialL) {
    __shared__ __align__(16) unsigned char As[3][BM * BKB];   // 48 KB
    __shared__ __align__(16) unsigned char Bs[3][BN * BKB];   // 24 KB

    const int tid  = threadIdx.x;
    const int w    = tid >> 6;        // wave 0..7
    const int lane = tid & 63;
    const int wm   = w >> 1;          // 0..3  (M quarter: rows wm*64..+63)
    const int wn   = w & 1;           // 0..1  (N half:   cols wn*64..+63)

    // XCD-stripe mapping (bijective: 1024 = 8 xcd * 16 by * 8 c8)
    const int id  = blockIdx.x;       // 0..1023
    const int xcd = id & 7;
    const int loc = id >> 3;          // 0..127
    const int by  = loc & 15;         // inner: A rows sweep while B fixed
    const int c8  = loc >> 4;         // 0..7
    const int rowBase = by * BM;
    const int colBase = (xcd * 8 + c8) * BN;

    const int lr = lane & 15;
    const int kq = lane >> 4;         // 0..3 = 16B k-seg

    // staging: chunk = 16 rows x 64B; lane l -> row l>>2, LDS seg l&3,
    // fetching pre-swizzled global seg (l&3)^f(l>>2), f(x)=(x^(x>>2))&3
    const int gseg = ((lane & 3) ^ ((lane >> 2) & 3) ^ ((lane >> 4) & 3));
    const unsigned char* aG = fN + (size_t)(rowBase + w * 32 + (lane >> 2)) * ROWB + gseg * 16;
    const unsigned char* bG = cN + (size_t)(colBase + w * 16 + (lane >> 2)) * ROWB + gseg * 16;

#define STAGE(buf, t)                                                        \
    do {                                                                     \
        gload_lds16(aG + (t) * BKB,             &As[buf][(w * 32) * BKB]);   \
        gload_lds16(aG + (t) * BKB + 16 * ROWB, &As[buf][(w * 32 + 16) * BKB]); \
        gload_lds16(bG + (t) * BKB,             &Bs[buf][(w * 16) * BKB]);   \
    } while (0)

    // read: lane wants global seg kq (16 contiguous k) at row base+lr:
    // LDS seg = kq ^ f(lr)
    const int segrd = (lane ^ (lane >> 2) ^ (lane >> 4)) & 3;
    const int loff  = lr * BKB + segrd * 16;     // per-lane offset in tile

    i32x4 acc[4][4] = {};

    // prologue: tiles 0,1 in flight (6 loads/wave)
    STAGE(0, 0);
    STAGE(1, 1);

    #pragma unroll
    for (int t = 0; t < NKT; ++t) {
        const int cur = t % 3;
        // outstanding per wave here: [tile t: 3, tile t+1: 3] ->
        // vmcnt(3) retires exactly tile t (issued 2 iters ago: ~no stall).
        if (t < NKT - 1) asm volatile("s_waitcnt vmcnt(3)" ::: "memory");
        else             asm volatile("s_waitcnt vmcnt(0)" ::: "memory");
        __builtin_amdgcn_s_barrier();    // publishes tile t's LDS + proves all
                                         // waves done reading buf[(t+2)%3]
        if (t + 2 < NKT) STAGE((t + 2) % 3, t + 2);

        i32x4 af[4], bb[4];
        #pragma unroll
        for (int m = 0; m < 4; ++m)
            af[m] = *(const i32x4*)&As[cur][(wm * 64 + m * 16) * BKB + loff];
        #pragma unroll
        for (int n = 0; n < 4; ++n)
            bb[n] = *(const i32x4*)&Bs[cur][(wn * 64 + n * 16) * BKB + loff];

        // compiler emits counted lgkmcnt between reads and consuming MFMAs.
        #pragma unroll
        for (int m = 0; m < 4; ++m)
            #pragma unroll
            for (int n = 0; n < 4; ++n)
                acc[m][n] = __builtin_amdgcn_mfma_i32_16x16x64_i8(
                                af[m], bb[n], acc[m][n], 0, 0, 0);
    }
#undef STAGE

    // ---- epilogue (exp2-domain): x' = (S-p)*k1, k1 = log2e/127^2 ----------
    // softplus = ln2 * log2(1 + 2^x'); the ln2 factor is folded into the
    // final division in finalize_kernel.  num_valid == N*(C-1) (constant).
    const float k1 = 1.44269504089e0f / 16129.0f;
    float lsum = 0.0f;
    #pragma unroll
    for (int m = 0; m < 4; ++m) {
        #pragma unroll
        for (int j = 0; j < 4; ++j) {
            const int gi  = rowBase + wm * 64 + m * 16 + kq * 4 + j;
            const float pk = pos[gi] * k1;       // hoisted out of n-loop
            const int  lab = labels[gi];
            #pragma unroll
            for (int n = 0; n < 4; ++n) {
                const int gj = colBase + wn * 64 + n * 16 + lr;
                const float xp = fmaf((float)acc[m][n][j], k1, -pk);
                const float l  = log2f(1.0f + exp2f(xp));   // softplus/ln2
                lsum += (gj != lab) ? l : 0.0f;
            }
        }
    }
    #pragma unroll
    for (int off = 32; off; off >>= 1) lsum += __shfl_xor(lsum, off);

    __syncthreads();                        // safe to reuse LDS
    float* s_sum = (float*)&As[0][0];
    if (lane == 0) s_sum[w] = lsum;
    __syncthreads();
    if (tid == 0) {
        float L = 0.0f;
        #pragma unroll
        for (int i = 0; i < 8; ++i) L += s_sum[i];
        partialL[id] = L;
    }
}

// ---------------- finalize: reduce 1024 per-block partials ----------------
__global__ __launch_bounds__(256) void finalize_kernel(
        const float* __restrict__ partialL, float* __restrict__ out) {
    __shared__ float s_sum[4];
    const int w    = threadIdx.x >> 6;
    const int lane = threadIdx.x & 63;

    float s = 0.0f;
    for (int i = threadIdx.x; i < NBLK; i += 256) s += partialL[i];
    #pragma unroll
    for (int off = 32; off; off >>= 1) s += __shfl_xor(s, off);
    if (lane == 0) s_sum[w] = s;
    __syncthreads();
    if (threadIdx.x == 0)
        out[0] = (s_sum[0] + s_sum[1] + s_sum[2] + s_sum[3])
                 * (0.69314718056f / NVALID);    // fold ln2 here
}

extern "C" void kernel_launch(void* const* d_in, const int* in_sizes, int n_in,
                              void* d_out, int out_size, void* d_ws, size_t ws_size,
                              hipStream_t stream) {
    const float* features = (const float*)d_in[0];   // [4096, 512]
    const float* centers  = (const float*)d_in[1];   // [8192, 512]
    const int*   labels   = (const int*)d_in[2];     // [4096]
    float* out = (float*)d_out;

    char* ws = (char*)d_ws;
    unsigned char* fN  = (unsigned char*)ws;                          // 2 MB
    unsigned char* cN  = (unsigned char*)(ws + (2u << 20));           // 4 MB
    float*         pos = (float*)(ws + (6u << 20));                   // 16 KB
    float*         partialL = (float*)(ws + (6u << 20) + (1u << 16)); // 4 KB

    normalize_kernel<<<(N_ROWS + C_ROWS) / 4, 256, 0, stream>>>(features, centers, fN, cN);
    posdot_kernel<<<N_ROWS / 4, 256, 0, stream>>>(fN, cN, labels, pos);

    fused_loss_kernel<<<NBLK, 512, 0, stream>>>(fN, cN, labels, pos, partialL);

    finalize_kernel<<<1, 256, 0, stream>>>(partialL, out);
}

// Round 16
// 40.893 us; speedup vs baseline: 5.8782x; 1.1241x over previous
//
#include <hip/hip_runtime.h>

#define N_ROWS 4096
#define D_DIM  512
#define ROWB   512              // bytes per i8 row
#define C_ROWS 8192
#define BM 256
#define BN 128
#define BKB 64                  // K-tile bytes = 64 i8 elems
#define NKT 8                   // 512 / 64
#define GXf (C_ROWS / BN)       // 64
#define GYf (N_ROWS / BM)       // 16
#define NBLK (GXf * GYf)        // 1024
#define NVALID 33550336.0f      // 4096 * 8191 (num_valid is provably constant)

typedef __attribute__((ext_vector_type(4))) int  i32x4;    // MFMA i8 frag/acc

#define AS1 __attribute__((address_space(1)))
#define AS3 __attribute__((address_space(3)))

__device__ __forceinline__ void gload_lds16(const void* g, void* l) {
    __builtin_amdgcn_global_load_lds((const AS1 unsigned int*)g,
                                     (AS3 unsigned int*)l, 16, 0, 0);
}

// ---------------- l2-normalize rows, fp32 -> i8 (q = round(127 x̂)) --------
__global__ __launch_bounds__(256) void normalize_kernel(
        const float* __restrict__ feat, const float* __restrict__ cent,
        unsigned char* __restrict__ fN, unsigned char* __restrict__ cN) {
    const int w    = threadIdx.x >> 6;
    const int lane = threadIdx.x & 63;
    const int row  = blockIdx.x * 4 + w;      // 0 .. 12287

    const float* src = (row < N_ROWS) ? feat + (size_t)row * D_DIM
                                      : cent + (size_t)(row - N_ROWS) * D_DIM;
    unsigned char* dst = (row < N_ROWS) ? fN + (size_t)row * ROWB
                                        : cN + (size_t)(row - N_ROWS) * ROWB;

    const float* r = src + lane * 8;
    float4 v0 = *(const float4*)(r);
    float4 v1 = *(const float4*)(r + 4);
    float ss = v0.x*v0.x + v0.y*v0.y + v0.z*v0.z + v0.w*v0.w
             + v1.x*v1.x + v1.y*v1.y + v1.z*v1.z + v1.w*v1.w;
    #pragma unroll
    for (int off = 32; off; off >>= 1) ss += __shfl_xor(ss, off);
    const float sc = 127.0f / fmaxf(sqrtf(ss), 1e-12f);

    int q0 = __float2int_rn(v0.x * sc), q1 = __float2int_rn(v0.y * sc);
    int q2 = __float2int_rn(v0.z * sc), q3 = __float2int_rn(v0.w * sc);
    int q4 = __float2int_rn(v1.x * sc), q5 = __float2int_rn(v1.y * sc);
    int q6 = __float2int_rn(v1.z * sc), q7 = __float2int_rn(v1.w * sc);

    uint2 o;
    o.x = (q0 & 0xFF) | ((q1 & 0xFF) << 8) | ((q2 & 0xFF) << 16) | ((q3 & 0xFF) << 24);
    o.y = (q4 & 0xFF) | ((q5 & 0xFF) << 8) | ((q6 & 0xFF) << 16) | ((q7 & 0xFF) << 24);
    *(uint2*)(dst + lane * 8) = o;
}

// ------------- pos_int[i] = fQ[i] . cQ[labels[i]]  (exact in fp32) ---------
__global__ __launch_bounds__(256) void posdot_kernel(
        const unsigned char* __restrict__ fN, const unsigned char* __restrict__ cN,
        const int* __restrict__ labels, float* __restrict__ pos) {
    const int w    = threadIdx.x >> 6;
    const int lane = threadIdx.x & 63;
    const int i    = blockIdx.x * 4 + w;
    const int lab  = labels[i];

    const uint2 a = *(const uint2*)(fN + (size_t)i   * ROWB + lane * 8);
    const uint2 b = *(const uint2*)(cN + (size_t)lab * ROWB + lane * 8);
    int s = 0;
    #pragma unroll
    for (int j = 0; j < 4; ++j) {
        s += (int)(signed char)((a.x >> (8 * j)) & 0xFF) *
             (int)(signed char)((b.x >> (8 * j)) & 0xFF);
        s += (int)(signed char)((a.y >> (8 * j)) & 0xFF) *
             (int)(signed char)((b.y >> (8 * j)) & 0xFF);
    }
    #pragma unroll
    for (int off = 32; off; off >>= 1) s += __shfl_xor(s, off);
    if (lane == 0) pos[i] = (float)s;    // |s| <= 8.3M < 2^24: exact
}

// ---------------- fused i8 GEMM + masked softplus reduction ----------------
// R14 structure (triple-buffer single-barrier, vmcnt(3) exact count) plus:
//  - softplus transcendentals as single-instr builtins (v_exp_f32/v_log_f32)
//  - s_setprio(1) around the MFMA cluster (T5: independent 2-blocks/CU give
//    the scheduler wave role diversity to arbitrate)
__global__ __launch_bounds__(512, 4) void fused_loss_kernel(
        const unsigned char* __restrict__ fN, const unsigned char* __restrict__ cN,
        const int* __restrict__ labels, const float* __restrict__ pos,
        float* __restrict__ partialL) {
    __shared__ __align__(16) unsigned char As[3][BM * BKB];   // 48 KB
    __shared__ __align__(16) unsigned char Bs[3][BN * BKB];   // 24 KB

    const int tid  = threadIdx.x;
    const int w    = tid >> 6;        // wave 0..7
    const int lane = tid & 63;
    const int wm   = w >> 1;          // 0..3  (M quarter: rows wm*64..+63)
    const int wn   = w & 1;           // 0..1  (N half:   cols wn*64..+63)

    // XCD-stripe mapping (bijective: 1024 = 8 xcd * 16 by * 8 c8)
    const int id  = blockIdx.x;       // 0..1023
    const int xcd = id & 7;
    const int loc = id >> 3;          // 0..127
    const int by  = loc & 15;         // inner: A rows sweep while B fixed
    const int c8  = loc >> 4;         // 0..7
    const int rowBase = by * BM;
    const int colBase = (xcd * 8 + c8) * BN;

    const int lr = lane & 15;
    const int kq = lane >> 4;         // 0..3 = 16B k-seg

    // staging: chunk = 16 rows x 64B; lane l -> row l>>2, LDS seg l&3,
    // fetching pre-swizzled global seg (l&3)^f(l>>2), f(x)=(x^(x>>2))&3
    const int gseg = ((lane & 3) ^ ((lane >> 2) & 3) ^ ((lane >> 4) & 3));
    const unsigned char* aG = fN + (size_t)(rowBase + w * 32 + (lane >> 2)) * ROWB + gseg * 16;
    const unsigned char* bG = cN + (size_t)(colBase + w * 16 + (lane >> 2)) * ROWB + gseg * 16;

#define STAGE(buf, t)                                                        \
    do {                                                                     \
        gload_lds16(aG + (t) * BKB,             &As[buf][(w * 32) * BKB]);   \
        gload_lds16(aG + (t) * BKB + 16 * ROWB, &As[buf][(w * 32 + 16) * BKB]); \
        gload_lds16(bG + (t) * BKB,             &Bs[buf][(w * 16) * BKB]);   \
    } while (0)

    // read: lane wants global seg kq (16 contiguous k) at row base+lr:
    // LDS seg = kq ^ f(lr)
    const int segrd = (lane ^ (lane >> 2) ^ (lane >> 4)) & 3;
    const int loff  = lr * BKB + segrd * 16;     // per-lane offset in tile

    i32x4 acc[4][4] = {};

    // prologue: tiles 0,1 in flight (6 loads/wave)
    STAGE(0, 0);
    STAGE(1, 1);

    #pragma unroll
    for (int t = 0; t < NKT; ++t) {
        const int cur = t % 3;
        // outstanding per wave here: [tile t: 3, tile t+1: 3] ->
        // vmcnt(3) retires exactly tile t (issued 2 iters ago: ~no stall).
        if (t < NKT - 1) asm volatile("s_waitcnt vmcnt(3)" ::: "memory");
        else             asm volatile("s_waitcnt vmcnt(0)" ::: "memory");
        __builtin_amdgcn_s_barrier();    // publishes tile t's LDS + proves all
                                         // waves done reading buf[(t+2)%3]
        if (t + 2 < NKT) STAGE((t + 2) % 3, t + 2);

        i32x4 af[4], bb[4];
        #pragma unroll
        for (int m = 0; m < 4; ++m)
            af[m] = *(const i32x4*)&As[cur][(wm * 64 + m * 16) * BKB + loff];
        #pragma unroll
        for (int n = 0; n < 4; ++n)
            bb[n] = *(const i32x4*)&Bs[cur][(wn * 64 + n * 16) * BKB + loff];

        // compiler emits counted lgkmcnt between reads and consuming MFMAs.
        __builtin_amdgcn_s_setprio(1);
        #pragma unroll
        for (int m = 0; m < 4; ++m)
            #pragma unroll
            for (int n = 0; n < 4; ++n)
                acc[m][n] = __builtin_amdgcn_mfma_i32_16x16x64_i8(
                                af[m], bb[n], acc[m][n], 0, 0, 0);
        __builtin_amdgcn_s_setprio(0);
    }
#undef STAGE

    // ---- epilogue (exp2-domain): x' = (S-p)*k1, k1 = log2e/127^2 ----------
    // softplus = ln2 * log2(1 + 2^x'); ln2 folded into finalize.
    // v_exp_f32 IS 2^x and v_log_f32 IS log2 -> single-instr via builtins.
    const float k1 = 1.44269504089e0f / 16129.0f;
    float lsum = 0.0f;
    #pragma unroll
    for (int m = 0; m < 4; ++m) {
        #pragma unroll
        for (int j = 0; j < 4; ++j) {
            const int gi  = rowBase + wm * 64 + m * 16 + kq * 4 + j;
            const float pk = pos[gi] * k1;       // hoisted out of n-loop
            const int  lab = labels[gi];
            #pragma unroll
            for (int n = 0; n < 4; ++n) {
                const int gj = colBase + wn * 64 + n * 16 + lr;
                const float xp = fmaf((float)acc[m][n][j], k1, -pk);
                const float l  = __builtin_amdgcn_logf(
                                     1.0f + __builtin_amdgcn_exp2f(xp));
                lsum += (gj != lab) ? l : 0.0f;
            }
        }
    }
    #pragma unroll
    for (int off = 32; off; off >>= 1) lsum += __shfl_xor(lsum, off);

    __syncthreads();                        // safe to reuse LDS
    float* s_sum = (float*)&As[0][0];
    if (lane == 0) s_sum[w] = lsum;
    __syncthreads();
    if (tid == 0) {
        float L = 0.0f;
        #pragma unroll
        for (int i = 0; i < 8; ++i) L += s_sum[i];
        partialL[id] = L;
    }
}

// ---------------- finalize: reduce 1024 per-block partials ----------------
__global__ __launch_bounds__(256) void finalize_kernel(
        const float* __restrict__ partialL, float* __restrict__ out) {
    __shared__ float s_sum[4];
    const int w    = threadIdx.x >> 6;
    const int lane = threadIdx.x & 63;

    float s = 0.0f;
    for (int i = threadIdx.x; i < NBLK; i += 256) s += partialL[i];
    #pragma unroll
    for (int off = 32; off; off >>= 1) s += __shfl_xor(s, off);
    if (lane == 0) s_sum[w] = s;
    __syncthreads();
    if (threadIdx.x == 0)
        out[0] = (s_sum[0] + s_sum[1] + s_sum[2] + s_sum[3])
                 * (0.69314718056f / NVALID);    // fold ln2 here
}

extern "C" void kernel_launch(void* const* d_in, const int* in_sizes, int n_in,
                              void* d_out, int out_size, void* d_ws, size_t ws_size,
                              hipStream_t stream) {
    const float* features = (const float*)d_in[0];   // [4096, 512]
    const float* centers  = (const float*)d_in[1];   // [8192, 512]
    const int*   labels   = (const int*)d_in[2];     // [4096]
    float* out = (float*)d_out;

    char* ws = (char*)d_ws;
    unsigned char* fN  = (unsigned char*)ws;                          // 2 MB
    unsigned char* cN  = (unsigned char*)(ws + (2u << 20));           // 4 MB
    float*         pos = (float*)(ws + (6u << 20));                   // 16 KB
    float*         partialL = (float*)(ws + (6u << 20) + (1u << 16)); // 4 KB

    normalize_kernel<<<(N_ROWS + C_ROWS) / 4, 256, 0, stream>>>(features, centers, fN, cN);
    posdot_kernel<<<N_ROWS / 4, 256, 0, stream>>>(fN, cN, labels, pos);

    fused_loss_kernel<<<NBLK, 512, 0, stream>>>(fN, cN, labels, pos, partialL);

    finalize_kernel<<<1, 256, 0, stream>>>(partialL, out);
}

// Round 17
// 39.678 us; speedup vs baseline: 6.0582x; 1.0306x over previous
//
#include <hip/hip_runtime.h>

#define N_ROWS 4096
#define D_DIM  512
#define ROWB   512              // bytes per i8 row
#define C_ROWS 8192
#define BM 256
#define BN 128
#define BKB 64                  // K-tile bytes = 64 i8 elems
#define NKT 8                   // 512 / 64
#define GXf (C_ROWS / BN)       // 64
#define GYf (N_ROWS / BM)       // 16
#define NBLK (GXf * GYf)        // 1024
#define NVALID 33550336.0f      // 4096 * 8191 (num_valid is provably constant)

typedef __attribute__((ext_vector_type(4))) int  i32x4;    // MFMA i8 frag/acc

#define AS1 __attribute__((address_space(1)))
#define AS3 __attribute__((address_space(3)))

__device__ __forceinline__ void gload_lds16(const void* g, void* l) {
    __builtin_amdgcn_global_load_lds((const AS1 unsigned int*)g,
                                     (AS3 unsigned int*)l, 16, 0, 0);
}

// ---------------- l2-normalize rows, fp32 -> i8 (q = round(127 x̂)) --------
__global__ __launch_bounds__(256) void normalize_kernel(
        const float* __restrict__ feat, const float* __restrict__ cent,
        unsigned char* __restrict__ fN, unsigned char* __restrict__ cN) {
    const int w    = threadIdx.x >> 6;
    const int lane = threadIdx.x & 63;
    const int row  = blockIdx.x * 4 + w;      // 0 .. 12287

    const float* src = (row < N_ROWS) ? feat + (size_t)row * D_DIM
                                      : cent + (size_t)(row - N_ROWS) * D_DIM;
    unsigned char* dst = (row < N_ROWS) ? fN + (size_t)row * ROWB
                                        : cN + (size_t)(row - N_ROWS) * ROWB;

    const float* r = src + lane * 8;
    float4 v0 = *(const float4*)(r);
    float4 v1 = *(const float4*)(r + 4);
    float ss = v0.x*v0.x + v0.y*v0.y + v0.z*v0.z + v0.w*v0.w
             + v1.x*v1.x + v1.y*v1.y + v1.z*v1.z + v1.w*v1.w;
    #pragma unroll
    for (int off = 32; off; off >>= 1) ss += __shfl_xor(ss, off);
    const float sc = 127.0f / fmaxf(sqrtf(ss), 1e-12f);

    int q0 = __float2int_rn(v0.x * sc), q1 = __float2int_rn(v0.y * sc);
    int q2 = __float2int_rn(v0.z * sc), q3 = __float2int_rn(v0.w * sc);
    int q4 = __float2int_rn(v1.x * sc), q5 = __float2int_rn(v1.y * sc);
    int q6 = __float2int_rn(v1.z * sc), q7 = __float2int_rn(v1.w * sc);

    uint2 o;
    o.x = (q0 & 0xFF) | ((q1 & 0xFF) << 8) | ((q2 & 0xFF) << 16) | ((q3 & 0xFF) << 24);
    o.y = (q4 & 0xFF) | ((q5 & 0xFF) << 8) | ((q6 & 0xFF) << 16) | ((q7 & 0xFF) << 24);
    *(uint2*)(dst + lane * 8) = o;
}

// ------------- pos_int[i] = fQ[i] . cQ[labels[i]]  (exact in fp32) ---------
__global__ __launch_bounds__(256) void posdot_kernel(
        const unsigned char* __restrict__ fN, const unsigned char* __restrict__ cN,
        const int* __restrict__ labels, float* __restrict__ pos) {
    const int w    = threadIdx.x >> 6;
    const int lane = threadIdx.x & 63;
    const int i    = blockIdx.x * 4 + w;
    const int lab  = labels[i];

    const uint2 a = *(const uint2*)(fN + (size_t)i   * ROWB + lane * 8);
    const uint2 b = *(const uint2*)(cN + (size_t)lab * ROWB + lane * 8);
    int s = 0;
    #pragma unroll
    for (int j = 0; j < 4; ++j) {
        s += (int)(signed char)((a.x >> (8 * j)) & 0xFF) *
             (int)(signed char)((b.x >> (8 * j)) & 0xFF);
        s += (int)(signed char)((a.y >> (8 * j)) & 0xFF) *
             (int)(signed char)((b.y >> (8 * j)) & 0xFF);
    }
    #pragma unroll
    for (int off = 32; off; off >>= 1) s += __shfl_xor(s, off);
    if (lane == 0) pos[i] = (float)s;    // |s| <= 8.3M < 2^24: exact
}

// ---------------- fused i8 GEMM + softplus reduction (NO mask) -------------
// R15 structure (triple-buffer single-barrier, vmcnt(3), setprio, exp2-domain
// epilogue) with the EXACT-DIAGONAL trick: for j == label_i, S_int == pos_int
// exactly (identical integer dots) -> x' = 0 -> log2(1+2^0) = 1.0 exactly.
// So sum ALL terms unmasked and subtract 4096 x 1.0 in finalize.  Removes
// per-element gj/compare/select and all labels loads from this kernel.
__global__ __launch_bounds__(512, 4) void fused_loss_kernel(
        const unsigned char* __restrict__ fN, const unsigned char* __restrict__ cN,
        const float* __restrict__ pos, float* __restrict__ partialL) {
    __shared__ __align__(16) unsigned char As[3][BM * BKB];   // 48 KB
    __shared__ __align__(16) unsigned char Bs[3][BN * BKB];   // 24 KB

    const int tid  = threadIdx.x;
    const int w    = tid >> 6;        // wave 0..7
    const int lane = tid & 63;
    const int wm   = w >> 1;          // 0..3  (M quarter: rows wm*64..+63)
    const int wn   = w & 1;           // 0..1  (N half:   cols wn*64..+63)

    // XCD-stripe mapping (bijective: 1024 = 8 xcd * 16 by * 8 c8)
    const int id  = blockIdx.x;       // 0..1023
    const int xcd = id & 7;
    const int loc = id >> 3;          // 0..127
    const int by  = loc & 15;         // inner: A rows sweep while B fixed
    const int c8  = loc >> 4;         // 0..7
    const int rowBase = by * BM;
    const int colBase = (xcd * 8 + c8) * BN;

    const int lr = lane & 15;
    const int kq = lane >> 4;         // 0..3 = 16B k-seg

    // staging: chunk = 16 rows x 64B; lane l -> row l>>2, LDS seg l&3,
    // fetching pre-swizzled global seg (l&3)^f(l>>2), f(x)=(x^(x>>2))&3
    const int gseg = ((lane & 3) ^ ((lane >> 2) & 3) ^ ((lane >> 4) & 3));
    const unsigned char* aG = fN + (size_t)(rowBase + w * 32 + (lane >> 2)) * ROWB + gseg * 16;
    const unsigned char* bG = cN + (size_t)(colBase + w * 16 + (lane >> 2)) * ROWB + gseg * 16;

#define STAGE(buf, t)                                                        \
    do {                                                                     \
        gload_lds16(aG + (t) * BKB,             &As[buf][(w * 32) * BKB]);   \
        gload_lds16(aG + (t) * BKB + 16 * ROWB, &As[buf][(w * 32 + 16) * BKB]); \
        gload_lds16(bG + (t) * BKB,             &Bs[buf][(w * 16) * BKB]);   \
    } while (0)

    // read: lane wants global seg kq (16 contiguous k) at row base+lr:
    // LDS seg = kq ^ f(lr)
    const int segrd = (lane ^ (lane >> 2) ^ (lane >> 4)) & 3;
    const int loff  = lr * BKB + segrd * 16;     // per-lane offset in tile

    i32x4 acc[4][4] = {};

    // prologue: tiles 0,1 in flight (6 loads/wave)
    STAGE(0, 0);
    STAGE(1, 1);

    #pragma unroll
    for (int t = 0; t < NKT; ++t) {
        const int cur = t % 3;
        // outstanding per wave here: [tile t: 3, tile t+1: 3] ->
        // vmcnt(3) retires exactly tile t (issued 2 iters ago: ~no stall).
        if (t < NKT - 1) asm volatile("s_waitcnt vmcnt(3)" ::: "memory");
        else             asm volatile("s_waitcnt vmcnt(0)" ::: "memory");
        __builtin_amdgcn_s_barrier();    // publishes tile t's LDS + proves all
                                         // waves done reading buf[(t+2)%3]
        if (t + 2 < NKT) STAGE((t + 2) % 3, t + 2);

        i32x4 af[4], bb[4];
        #pragma unroll
        for (int m = 0; m < 4; ++m)
            af[m] = *(const i32x4*)&As[cur][(wm * 64 + m * 16) * BKB + loff];
        #pragma unroll
        for (int n = 0; n < 4; ++n)
            bb[n] = *(const i32x4*)&Bs[cur][(wn * 64 + n * 16) * BKB + loff];

        // compiler emits counted lgkmcnt between reads and consuming MFMAs.
        __builtin_amdgcn_s_setprio(1);
        #pragma unroll
        for (int m = 0; m < 4; ++m)
            #pragma unroll
            for (int n = 0; n < 4; ++n)
                acc[m][n] = __builtin_amdgcn_mfma_i32_16x16x64_i8(
                                af[m], bb[n], acc[m][n], 0, 0, 0);
        __builtin_amdgcn_s_setprio(0);
    }
#undef STAGE

    // ---- epilogue (exp2-domain, unmasked): x' = (S-p)*k1, k1=log2e/127^2 --
    // softplus/ln2 = log2(1 + 2^x'); diagonal terms contribute exactly 1.0
    // each and are subtracted (4096 total) in finalize.
    const float k1 = 1.44269504089e0f / 16129.0f;
    float lsum = 0.0f;
    #pragma unroll
    for (int m = 0; m < 4; ++m) {
        #pragma unroll
        for (int j = 0; j < 4; ++j) {
            const int gi  = rowBase + wm * 64 + m * 16 + kq * 4 + j;
            const float pk = pos[gi] * k1;       // hoisted out of n-loop
            #pragma unroll
            for (int n = 0; n < 4; ++n) {
                const float xp = fmaf((float)acc[m][n][j], k1, -pk);
                lsum += __builtin_amdgcn_logf(1.0f + __builtin_amdgcn_exp2f(xp));
            }
        }
    }
    #pragma unroll
    for (int off = 32; off; off >>= 1) lsum += __shfl_xor(lsum, off);

    __syncthreads();                        // safe to reuse LDS
    float* s_sum = (float*)&As[0][0];
    if (lane == 0) s_sum[w] = lsum;
    __syncthreads();
    if (tid == 0) {
        float L = 0.0f;
        #pragma unroll
        for (int i = 0; i < 8; ++i) L += s_sum[i];
        partialL[id] = L;
    }
}

// ---------------- finalize: reduce 1024 per-block partials ----------------
__global__ __launch_bounds__(256) void finalize_kernel(
        const float* __restrict__ partialL, float* __restrict__ out) {
    __shared__ float s_sum[4];
    const int w    = threadIdx.x >> 6;
    const int lane = threadIdx.x & 63;

    float s = 0.0f;
    for (int i = threadIdx.x; i < NBLK; i += 256) s += partialL[i];
    #pragma unroll
    for (int off = 32; off; off >>= 1) s += __shfl_xor(s, off);
    if (lane == 0) s_sum[w] = s;
    __syncthreads();
    if (threadIdx.x == 0)
        out[0] = (s_sum[0] + s_sum[1] + s_sum[2] + s_sum[3] - 4096.0f)
                 * (0.69314718056f / NVALID);    // drop exact diagonal, fold ln2
}

extern "C" void kernel_launch(void* const* d_in, const int* in_sizes, int n_in,
                              void* d_out, int out_size, void* d_ws, size_t ws_size,
                              hipStream_t stream) {
    const float* features = (const float*)d_in[0];   // [4096, 512]
    const float* centers  = (const float*)d_in[1];   // [8192, 512]
    const int*   labels   = (const int*)d_in[2];     // [4096]
    float* out = (float*)d_out;

    char* ws = (char*)d_ws;
    unsigned char* fN  = (unsigned char*)ws;                          // 2 MB
    unsigned char* cN  = (unsigned char*)(ws + (2u << 20));           // 4 MB
    float*         pos = (float*)(ws + (6u << 20));                   // 16 KB
    float*         partialL = (float*)(ws + (6u << 20) + (1u << 16)); // 4 KB

    normalize_kernel<<<(N_ROWS + C_ROWS) / 4, 256, 0, stream>>>(features, centers, fN, cN);
    posdot_kernel<<<N_ROWS / 4, 256, 0, stream>>>(fN, cN, labels, pos);

    fused_loss_kernel<<<NBLK, 512, 0, stream>>>(fN, cN, pos, partialL);

    finalize_kernel<<<1, 256, 0, stream>>>(partialL, out);
}